// Round 3
// baseline (369.036 us; speedup 1.0000x reference)
//
#include <hip/hip_runtime.h>

typedef unsigned short ushort_t;
typedef __attribute__((ext_vector_type(8))) __bf16 bf16x8;
typedef __attribute__((ext_vector_type(8))) unsigned short ushort8;
typedef __attribute__((ext_vector_type(4))) unsigned short ushort4v;
typedef __attribute__((ext_vector_type(4))) float floatx4;

__device__ inline unsigned short f2bf(float f) {
  union { float f; unsigned u; } x; x.f = f;
  return (unsigned short)((x.u + 0x7FFFu + ((x.u >> 16) & 1u)) >> 16);
}
__device__ inline float bf2f(unsigned short u) {
  union { unsigned u; float f; } x; x.u = ((unsigned)u) << 16;
  return x.f;
}

// ---------------- fp32 -> bf16 convert ---------------------------------------
__global__ void cvt_f32_bf16(const float* __restrict__ in, ushort_t* __restrict__ out, int n) {
  int i = (blockIdx.x * blockDim.x + threadIdx.x) * 8;
  if (i >= n) return;
  const float4* p = (const float4*)(in + i);
  float4 a = p[0], b = p[1];
  ushort8 o;
  o[0] = f2bf(a.x); o[1] = f2bf(a.y); o[2] = f2bf(a.z); o[3] = f2bf(a.w);
  o[4] = f2bf(b.x); o[5] = f2bf(b.y); o[6] = f2bf(b.z); o[7] = f2bf(b.w);
  *(ushort8*)(out + i) = o;
}

// ---------------- async global->LDS ------------------------------------------
__device__ inline void gload_lds16(const void* g, void* l) {
  __builtin_amdgcn_global_load_lds(
      (const __attribute__((address_space(1))) unsigned int*)g,
      (__attribute__((address_space(3))) unsigned int*)l, 16, 0, 0);
}

__device__ inline void store_out(float* p, float v) { *p = v; }
__device__ inline void store_out(ushort_t* p, float v) { *p = f2bf(v); }

// ---------------- 128x128-tile NT GEMM: C = A[M,KK]*B[N,KK]^T (+bias) --------
template <typename OutT, bool BIAS, int KK>
__global__ void gemm_bt(const ushort_t* __restrict__ A, const ushort_t* __restrict__ Bm,
                        const float* __restrict__ bias, OutT* __restrict__ C,
                        int M, int N, long sA_, long sB_, long sBias_, long sC_) {
  // XCD-aware remap: contiguous tile-run per XCD (dispatch round-robins % 8).
  int gx = gridDim.x, gxy = gridDim.x * gridDim.y;
  int flat = blockIdx.x + gx * blockIdx.y + gxy * blockIdx.z;
  int total = gxy * gridDim.z;
  int per = total >> 3;
  int nf = (flat & 7) * per + (flat >> 3);
  int bz = nf / gxy; int rem = nf - bz * gxy;
  int by = rem / gx; int bx = rem - by * gx;

  A += (long)bz * sA_; Bm += (long)bz * sB_; C += (long)bz * sC_;
  if (BIAS) bias += (long)bz * sBias_;

  __shared__ ushort_t sA[128 * 32];
  __shared__ ushort_t sB[128 * 32];

  int t = threadIdx.x;
  int w = t >> 6, l = t & 63;
  int wy = w >> 1, wx = w & 1;
  int quad = l >> 4, m16 = l & 15;
  int mBase = by * 128, nBase = bx * 128;

  int r = l >> 2, pb = l & 3;
  int swzS = (r ^ (r >> 2)) & 3;
  int sRow0 = w * 32 + r;
  int sCol = (pb ^ swzS) * 8;
  const ushort_t* gA0 = A + (long)(mBase + sRow0) * KK + sCol;
  const ushort_t* gA1 = gA0 + 16 * KK;
  const ushort_t* gB0 = Bm + (long)(nBase + sRow0) * KK + sCol;
  const ushort_t* gB1 = gB0 + 16 * KK;
  ushort_t* lA0 = sA + (w * 2) * 512;
  ushort_t* lA1 = lA0 + 512;
  ushort_t* lB0 = sB + (w * 2) * 512;
  ushort_t* lB1 = lB0 + 512;

  int swzR = (m16 ^ (m16 >> 2)) & 3;
  int aOff = (wy * 64 + m16) * 32 + (quad ^ swzR) * 8;
  int bOff = (wx * 64 + m16) * 32 + (quad ^ swzR) * 8;

  floatx4 acc[4][4] = {};

  for (int kt = 0; kt < KK; kt += 32) {
    __syncthreads();
    gload_lds16(gA0 + kt, lA0);
    gload_lds16(gA1 + kt, lA1);
    gload_lds16(gB0 + kt, lB0);
    gload_lds16(gB1 + kt, lB1);
    __syncthreads();
    bf16x8 af[4], bfr[4];
#pragma unroll
    for (int i = 0; i < 4; ++i) af[i] = *(const bf16x8*)(sA + aOff + i * 16 * 32);
#pragma unroll
    for (int i = 0; i < 4; ++i) bfr[i] = *(const bf16x8*)(sB + bOff + i * 16 * 32);
#pragma unroll
    for (int mi = 0; mi < 4; ++mi)
#pragma unroll
      for (int ni = 0; ni < 4; ++ni)
        acc[mi][ni] = __builtin_amdgcn_mfma_f32_16x16x32_bf16(af[mi], bfr[ni], acc[mi][ni], 0, 0, 0);
  }

#pragma unroll
  for (int ni = 0; ni < 4; ++ni) {
    int n = nBase + wx * 64 + ni * 16 + m16;
    float bb = BIAS ? bias[n] : 0.f;
#pragma unroll
    for (int mi = 0; mi < 4; ++mi) {
      int m0 = mBase + wy * 64 + mi * 16 + quad * 4;
      floatx4 v = acc[mi][ni];
#pragma unroll
      for (int rr = 0; rr < 4; ++rr)
        store_out(&C[(long)(m0 + rr) * N + n], v[rr] + bb);
    }
  }
}

// ---------------- bf16 transpose: X[4][4096][1024] -> XT[4][1024][4096] ------
__global__ void transpose_bf(const ushort_t* __restrict__ in, ushort_t* __restrict__ out) {
  int nt = blockIdx.x, ct = blockIdx.y, b = blockIdx.z;  // 64 x 16 x 4
  __shared__ ushort_t tile[64 * 68];  // stride 68 shorts: 8B-aligned rows, low conflict
  int t = threadIdx.x;
  int r = t >> 3, c8 = (t & 7) * 8;
  long ibase = ((long)b * 4096 + nt * 64) * 1024 + (long)ct * 64;
  ushort8 v0 = *(const ushort8*)(in + ibase + (long)r * 1024 + c8);
  ushort8 v1 = *(const ushort8*)(in + ibase + (long)(r + 32) * 1024 + c8);
  ushort4v a0 = {v0[0], v0[1], v0[2], v0[3]}, a1 = {v0[4], v0[5], v0[6], v0[7]};
  ushort4v b0 = {v1[0], v1[1], v1[2], v1[3]}, b1 = {v1[4], v1[5], v1[6], v1[7]};
  *(ushort4v*)(tile + r * 68 + c8) = a0;
  *(ushort4v*)(tile + r * 68 + c8 + 4) = a1;
  *(ushort4v*)(tile + (r + 32) * 68 + c8) = b0;
  *(ushort4v*)(tile + (r + 32) * 68 + c8 + 4) = b1;
  __syncthreads();
  int c = t >> 3, n0 = (t & 7) * 8;
#pragma unroll
  for (int half = 0; half < 2; ++half) {
    int cc = c + half * 32;
    ushort8 o;
#pragma unroll
    for (int i = 0; i < 8; ++i) o[i] = tile[(n0 + i) * 68 + cc];
    *(ushort8*)(out + ((long)b * 1024 + ct * 64 + cc) * 4096 + nt * 64 + n0) = o;
  }
}

// ---------------- column sums: s[b][c] = sum_n Xbf[b][n][c] ------------------
__global__ void colsum(const ushort_t* __restrict__ X, float* __restrict__ s) {
  int b = blockIdx.x, ct = blockIdx.y;  // 4 x 16
  int t = threadIdx.x;
  int c8 = (t & 7) * 8, g = t >> 3;  // 32 n-groups of 128
  long base = (long)b * 4194304 + (long)ct * 64;
  float acc[8] = {};
  for (int n = g * 128; n < g * 128 + 128; ++n) {
    ushort8 v = *(const ushort8*)(X + base + (long)n * 1024 + c8);
#pragma unroll
    for (int i = 0; i < 8; ++i) acc[i] += bf2f(v[i]);
  }
  __shared__ float red[32 * 64];
#pragma unroll
  for (int i = 0; i < 8; ++i) red[g * 64 + c8 + i] = acc[i];
  __syncthreads();
  if (t < 64) {
    float sum = 0.f;
#pragma unroll
    for (int gg = 0; gg < 32; ++gg) sum += red[gg * 64 + t];
    s[b * 1024 + ct * 64 + t] = sum;
  }
}

// ---------------- u = Wk s, w = Wv s ----------------------------------------
__global__ void gemv_uw(const ushort_t* __restrict__ Wkbf, const ushort_t* __restrict__ Wvbf,
                        const float* __restrict__ s, float* __restrict__ u, float* __restrict__ w) {
  int b = blockIdx.x, rt = blockIdx.y;  // 4 x 8 (128 rows each of u,w per block)
  __shared__ float ss[1024];
  int t = threadIdx.x;
  *(float4*)(ss + t * 4) = *(const float4*)(s + b * 1024 + t * 4);
  __syncthreads();
  int wv = t >> 6, l = t & 63;
  int rl = l >> 3, j8 = (l & 7) * 8;
#pragma unroll
  for (int m = 0; m < 2; ++m) {
    const ushort_t* W = m ? Wvbf : Wkbf;
    float* o = m ? w : u;
    for (int rb = 0; rb < 128; rb += 32) {
      int row = rt * 128 + rb + wv * 8 + rl;
      float acc = 0.f;
      for (int k = 0; k < 1024; k += 64) {
        ushort8 wv8 = *(const ushort8*)(W + (long)row * 1024 + k + j8);
#pragma unroll
        for (int i = 0; i < 8; ++i) acc += bf2f(wv8[i]) * ss[k + j8 + i];
      }
      acc += __shfl_xor(acc, 1);
      acc += __shfl_xor(acc, 2);
      acc += __shfl_xor(acc, 4);
      if ((l & 7) == 0) o[b * 1024 + row] = acc;
    }
  }
}

// ---------------- ktv[b,h] = T1_b[h-rows]*Wv_h^T + rank-1 corrections -------
__global__ void ktv_small(const ushort_t* __restrict__ T1, const ushort_t* __restrict__ Wvbf,
                          const float* __restrict__ u, const float* __restrict__ w,
                          const float* __restrict__ bk, const float* __restrict__ bv,
                          float* __restrict__ ktv) {
  int bh = blockIdx.x;  // 64
  int b = bh >> 4, h = bh & 15;
  __shared__ ushort_t sA[64 * 32];
  __shared__ ushort_t sB[64 * 32];
  int t = threadIdx.x, wv = t >> 6, l = t & 63;
  int quad = l >> 4, m16 = l & 15;
  int r = l >> 2, pb = l & 3;
  int swzS = (r ^ (r >> 2)) & 3;
  int sCol = (pb ^ swzS) * 8;
  const ushort_t* gA = T1 + (long)b * 1048576 + (long)(h * 64 + wv * 16 + r) * 1024 + sCol;
  const ushort_t* gB = Wvbf + (long)(h * 64 + wv * 16 + r) * 1024 + sCol;
  ushort_t* lA = sA + wv * 512;
  ushort_t* lB = sB + wv * 512;
  int swzR = (m16 ^ (m16 >> 2)) & 3;
  int aOff = (wv * 16 + m16) * 32 + (quad ^ swzR) * 8;
  floatx4 acc[4] = {};
  for (int kt = 0; kt < 1024; kt += 32) {
    __syncthreads();
    gload_lds16(gA + kt, lA);
    gload_lds16(gB + kt, lB);
    __syncthreads();
    bf16x8 af = *(const bf16x8*)(sA + aOff);
#pragma unroll
    for (int j = 0; j < 4; ++j) {
      bf16x8 bf = *(const bf16x8*)(sB + (j * 16 + m16) * 32 + (quad ^ swzR) * 8);
      acc[j] = __builtin_amdgcn_mfma_f32_16x16x32_bf16(af, bf, acc[j], 0, 0, 0);
    }
  }
  float* p = ktv + (long)bh * 4096;
#pragma unroll
  for (int j = 0; j < 4; ++j) {
    int e = j * 16 + m16;
    float bve = bv[h * 64 + e];
    float wpe = w[b * 1024 + h * 64 + e] + 4096.f * bve;
#pragma unroll
    for (int rr = 0; rr < 4; ++rr) {
      int d = wv * 16 + quad * 4 + rr;
      float corr = u[b * 1024 + h * 64 + d] * bve + bk[h * 64 + d] * wpe;
      p[d * 64 + e] = acc[j][rr] + corr;
    }
  }
}

// ---------------- build W2T (bf16) and bias2 (fp32) -------------------------
__global__ void make_w2(const float* __restrict__ Wq, const float* __restrict__ bq,
                        const float* __restrict__ ktv, ushort_t* __restrict__ W2T,
                        float* __restrict__ bias2, float scale) {
  int bh = blockIdx.x, cq = blockIdx.y;
  int b = bh >> 4, h = bh & 15;
  __shared__ float sKTV[64 * 64];
  __shared__ float sW[64 * 64];
  int t = threadIdx.x;
  for (int i = t * 4; i < 4096; i += 1024)
    *(float4*)(sKTV + i) = *(const float4*)(ktv + (long)bh * 4096 + i);
  __syncthreads();
  if (cq == 0 && t < 64) {
    float s = 0.f;
    for (int d = 0; d < 64; ++d) s += bq[h * 64 + d] * sKTV[d * 64 + t];
    bias2[b * 1024 + h * 64 + t] = s * scale;
  }
  int e = t >> 2, c0 = (t & 3) * 16;
  for (int ct = cq * 256; ct < cq * 256 + 256; ct += 64) {
    __syncthreads();
    {
      int d = t >> 2, cc = (t & 3) * 16;
#pragma unroll
      for (int j = 0; j < 16; j += 4)
        *(float4*)(sW + d * 64 + cc + j) =
            *(const float4*)(Wq + (long)(h * 64 + d) * 1024 + ct + cc + j);
    }
    __syncthreads();
    float outv[16] = {};
    for (int d = 0; d < 64; ++d) {
      float kv = sKTV[d * 64 + e];
#pragma unroll
      for (int j = 0; j < 16; ++j) outv[j] += sW[d * 64 + c0 + j] * kv;
    }
    ushort8 o0, o1;
#pragma unroll
    for (int j = 0; j < 8; ++j) { o0[j] = f2bf(outv[j] * scale); o1[j] = f2bf(outv[8 + j] * scale); }
    ushort_t* dst = W2T + ((long)(b * 1024 + h * 64 + e)) * 1024 + ct + c0;
    *(ushort8*)dst = o0;
    *(ushort8*)(dst + 8) = o1;
  }
}

// ---------------- launch -----------------------------------------------------
extern "C" void kernel_launch(void* const* d_in, const int* in_sizes, int n_in,
                              void* d_out, int out_size, void* d_ws, size_t ws_size,
                              hipStream_t stream) {
  (void)in_sizes; (void)n_in; (void)out_size; (void)ws_size;
  const float* tens = (const float*)d_in[0];
  const float* Wq = (const float*)d_in[1];
  const float* bq = (const float*)d_in[2];
  const float* Wk = (const float*)d_in[3];
  const float* bk = (const float*)d_in[4];
  const float* Wv = (const float*)d_in[5];
  const float* bv = (const float*)d_in[6];
  float* out = (float*)d_out;

  char* wsp = (char*)d_ws;
  ushort_t* Xbf  = (ushort_t*)(wsp);               // 33,554,432 B
  ushort_t* XTbf = (ushort_t*)(wsp + 33554432);    // 33,554,432 B
  ushort_t* Gbf  = (ushort_t*)(wsp + 67108864);    //  8,388,608 B
  ushort_t* T1   = (ushort_t*)(wsp + 75497472);    //  8,388,608 B
  ushort_t* Wkbf = (ushort_t*)(wsp + 83886080);    //  2,097,152 B
  ushort_t* Wvbf = (ushort_t*)(wsp + 85983232);    //  2,097,152 B
  ushort_t* W2T  = (ushort_t*)(wsp + 88080384);    //  8,388,608 B
  float*    ktv  = (float*)(wsp + 96468992);       //  1,048,576 B
  float*    s    = (float*)(wsp + 97517568);       //     16,384 B
  float*    u    = (float*)(wsp + 97533952);       //     16,384 B
  float*    w    = (float*)(wsp + 97550336);       //     16,384 B
  float*    bias2= (float*)(wsp + 97566720);       //     16,384 B

  const float scale = (1.0f / 8.0f) / 64.0f;  // 1/sqrt(DH)/sqrt(N)

  hipLaunchKernelGGL(cvt_f32_bf16, dim3(8192), dim3(256), 0, stream, tens, Xbf, 16777216);
  hipLaunchKernelGGL(cvt_f32_bf16, dim3(512), dim3(256), 0, stream, Wk, Wkbf, 1048576);
  hipLaunchKernelGGL(cvt_f32_bf16, dim3(512), dim3(256), 0, stream, Wv, Wvbf, 1048576);

  hipLaunchKernelGGL(transpose_bf, dim3(64, 16, 4), dim3(256), 0, stream, Xbf, XTbf);
  hipLaunchKernelGGL(colsum, dim3(4, 16), dim3(256), 0, stream, Xbf, s);

  // G_b = X_b^T X_b  (NT gemm on XT, K=4096) -> bf16
  hipLaunchKernelGGL((gemm_bt<ushort_t, false, 4096>), dim3(8, 8, 4), dim3(256), 0, stream,
                     XTbf, XTbf, (const float*)nullptr, Gbf, 1024, 1024,
                     4194304L, 4194304L, 0L, 1048576L);

  hipLaunchKernelGGL(gemv_uw, dim3(4, 8), dim3(256), 0, stream, Wkbf, Wvbf, s, u, w);

  // T1_b = Wk G_b  (G symmetric -> NT gemm) -> bf16
  hipLaunchKernelGGL((gemm_bt<ushort_t, false, 1024>), dim3(8, 8, 4), dim3(256), 0, stream,
                     Wkbf, Gbf, (const float*)nullptr, T1, 1024, 1024,
                     0L, 1048576L, 0L, 1048576L);

  hipLaunchKernelGGL(ktv_small, dim3(64), dim3(256), 0, stream, T1, Wvbf, u, w, bk, bv, ktv);
  hipLaunchKernelGGL(make_w2, dim3(64, 4), dim3(256), 0, stream, Wq, bq, ktv, W2T, bias2, scale);

  hipLaunchKernelGGL((gemm_bt<float, true, 1024>), dim3(8, 32, 4), dim3(256), 0, stream,
                     Xbf, W2T, bias2, out, 4096, 1024,
                     4194304L, 1048576L, 1024L, 4194304L);
}

// Round 4
// 349.151 us; speedup vs baseline: 1.0570x; 1.0570x over previous
//
#include <hip/hip_runtime.h>

typedef unsigned short ushort_t;
typedef __attribute__((ext_vector_type(8))) __bf16 bf16x8;
typedef __attribute__((ext_vector_type(8))) unsigned short ushort8;
typedef __attribute__((ext_vector_type(4))) unsigned short ushort4v;
typedef __attribute__((ext_vector_type(4))) float floatx4;

__device__ inline unsigned short f2bf(float f) {
  union { float f; unsigned u; } x; x.f = f;
  return (unsigned short)((x.u + 0x7FFFu + ((x.u >> 16) & 1u)) >> 16);
}
__device__ inline float bf2f(unsigned short u) {
  union { unsigned u; float f; } x; x.u = ((unsigned)u) << 16;
  return x.f;
}

// ---------------- fp32 -> bf16 convert (for Wk, Wv) --------------------------
__global__ void cvt_f32_bf16(const float* __restrict__ in, ushort_t* __restrict__ out, int n) {
  int i = (blockIdx.x * blockDim.x + threadIdx.x) * 8;
  if (i >= n) return;
  const float4* p = (const float4*)(in + i);
  float4 a = p[0], b = p[1];
  ushort8 o;
  o[0] = f2bf(a.x); o[1] = f2bf(a.y); o[2] = f2bf(a.z); o[3] = f2bf(a.w);
  o[4] = f2bf(b.x); o[5] = f2bf(b.y); o[6] = f2bf(b.z); o[7] = f2bf(b.w);
  *(ushort8*)(out + i) = o;
}

// ---------------- fused convert + transpose for X ----------------------------
// Reads fp32 X[4][4096][1024]; writes Xbf (same layout) and XTbf[4][1024][4096].
__global__ void cvt_tr(const float* __restrict__ in, ushort_t* __restrict__ Xb,
                       ushort_t* __restrict__ XT) {
  int nt = blockIdx.x, ct = blockIdx.y, b = blockIdx.z;  // 64 x 16 x 4
  __shared__ ushort_t tile[64 * 68];
  int t = threadIdx.x;
  int r = t >> 3, c8 = (t & 7) * 8;
  long ibase = ((long)b * 4096 + nt * 64) * 1024 + (long)ct * 64;
  const float4* s0 = (const float4*)(in + ibase + (long)r * 1024 + c8);
  const float4* s1 = (const float4*)(in + ibase + (long)(r + 32) * 1024 + c8);
  float4 a0 = s0[0], a1 = s0[1], b0 = s1[0], b1 = s1[1];
  ushort8 o0, o1;
  o0[0] = f2bf(a0.x); o0[1] = f2bf(a0.y); o0[2] = f2bf(a0.z); o0[3] = f2bf(a0.w);
  o0[4] = f2bf(a1.x); o0[5] = f2bf(a1.y); o0[6] = f2bf(a1.z); o0[7] = f2bf(a1.w);
  o1[0] = f2bf(b0.x); o1[1] = f2bf(b0.y); o1[2] = f2bf(b0.z); o1[3] = f2bf(b0.w);
  o1[4] = f2bf(b1.x); o1[5] = f2bf(b1.y); o1[6] = f2bf(b1.z); o1[7] = f2bf(b1.w);
  *(ushort8*)(Xb + ibase + (long)r * 1024 + c8) = o0;
  *(ushort8*)(Xb + ibase + (long)(r + 32) * 1024 + c8) = o1;
  ushort4v p0 = {o0[0], o0[1], o0[2], o0[3]}, p1 = {o0[4], o0[5], o0[6], o0[7]};
  ushort4v q0 = {o1[0], o1[1], o1[2], o1[3]}, q1 = {o1[4], o1[5], o1[6], o1[7]};
  *(ushort4v*)(tile + r * 68 + c8) = p0;
  *(ushort4v*)(tile + r * 68 + c8 + 4) = p1;
  *(ushort4v*)(tile + (r + 32) * 68 + c8) = q0;
  *(ushort4v*)(tile + (r + 32) * 68 + c8 + 4) = q1;
  __syncthreads();
  int c = t >> 3, n0 = (t & 7) * 8;
#pragma unroll
  for (int half = 0; half < 2; ++half) {
    int cc = c + half * 32;
    ushort8 o;
#pragma unroll
    for (int i = 0; i < 8; ++i) o[i] = tile[(n0 + i) * 68 + cc];
    *(ushort8*)(XT + ((long)b * 1024 + ct * 64 + cc) * 4096 + nt * 64 + n0) = o;
  }
}

// ---------------- async global->LDS ------------------------------------------
__device__ inline void gload_lds16(const void* g, void* l) {
  __builtin_amdgcn_global_load_lds(
      (const __attribute__((address_space(1))) unsigned int*)g,
      (__attribute__((address_space(3))) unsigned int*)l, 16, 0, 0);
}

__device__ inline void store_out(float* p, float v) { *p = v; }
__device__ inline void store_out(ushort_t* p, float v) { *p = f2bf(v); }

// ---------------- 128x128-tile NT GEMM, double-buffered, single-barrier ------
// C[bz] = A[batch] (M x KK slice) * B[batch] (N x KK slice)^T (+bias).
// LD = row stride of A/B; SPLITK slices of KK columns each (bz = batch*SPLITK+ks).
// K-loop: ONE barrier per k-step; loads for k+1 issued right after the barrier
// so the next barrier's vmcnt(0) drain waits on loads with a full iteration in
// flight (the m97 2-barrier structure drains them cold).
template <typename OutT, bool BIAS, int KK, int LD, int SPLITK>
__global__ void gemm_bt(const ushort_t* __restrict__ A, const ushort_t* __restrict__ Bm,
                        const float* __restrict__ bias, OutT* __restrict__ C,
                        int M, int N, long sA_, long sB_, long sBias_, long sC_) {
  // XCD-aware remap: contiguous tile-run per XCD (dispatch round-robins % 8).
  int gx = gridDim.x, gxy = gridDim.x * gridDim.y;
  int flat = blockIdx.x + gx * blockIdx.y + gxy * blockIdx.z;
  int total = gxy * gridDim.z;
  int per = total >> 3;
  int nf = (flat & 7) * per + (flat >> 3);
  int bz = nf / gxy; int rem = nf - bz * gxy;
  int by = rem / gx; int bx = rem - by * gx;

  int batch = bz / SPLITK, ks = bz - batch * SPLITK;
  A += (long)batch * sA_ + (long)ks * KK;
  Bm += (long)batch * sB_ + (long)ks * KK;
  C += (long)bz * sC_;

  __shared__ ushort_t sA[2][128 * 32];
  __shared__ ushort_t sB[2][128 * 32];

  int t = threadIdx.x;
  int w = t >> 6, l = t & 63;
  int wy = w >> 1, wx = w & 1;
  int quad = l >> 4, m16 = l & 15;
  int mBase = by * 128, nBase = bx * 128;

  int r = l >> 2, pb = l & 3;
  int swzS = (r ^ (r >> 2)) & 3;
  int sRow0 = w * 32 + r;
  int sCol = (pb ^ swzS) * 8;
  const ushort_t* gA0 = A + (long)(mBase + sRow0) * LD + sCol;
  const ushort_t* gA1 = gA0 + 16 * LD;
  const ushort_t* gB0 = Bm + (long)(nBase + sRow0) * LD + sCol;
  const ushort_t* gB1 = gB0 + 16 * LD;
  int lOff0 = (w * 2) * 512;
  int lOff1 = lOff0 + 512;

  int swzR = (m16 ^ (m16 >> 2)) & 3;
  int aOff = (wy * 64 + m16) * 32 + (quad ^ swzR) * 8;
  int bOff = (wx * 64 + m16) * 32 + (quad ^ swzR) * 8;

  floatx4 acc[4][4] = {};

  // prologue: stage k-tile 0 into buffer 0
  gload_lds16(gA0, &sA[0][lOff0]);
  gload_lds16(gA1, &sA[0][lOff1]);
  gload_lds16(gB0, &sB[0][lOff0]);
  gload_lds16(gB1, &sB[0][lOff1]);

  for (int kt = 0; kt < KK; kt += 32) {
    int cur = (kt >> 5) & 1;
    __syncthreads();  // buf[cur] data ready; buf[cur^1] readers done
    if (kt + 32 < KK) {
      int nxt = cur ^ 1;
      gload_lds16(gA0 + kt + 32, &sA[nxt][lOff0]);
      gload_lds16(gA1 + kt + 32, &sA[nxt][lOff1]);
      gload_lds16(gB0 + kt + 32, &sB[nxt][lOff0]);
      gload_lds16(gB1 + kt + 32, &sB[nxt][lOff1]);
    }
    bf16x8 af[4], bfr[4];
#pragma unroll
    for (int i = 0; i < 4; ++i) af[i] = *(const bf16x8*)(&sA[cur][0] + aOff + i * 16 * 32);
#pragma unroll
    for (int i = 0; i < 4; ++i) bfr[i] = *(const bf16x8*)(&sB[cur][0] + bOff + i * 16 * 32);
#pragma unroll
    for (int mi = 0; mi < 4; ++mi)
#pragma unroll
      for (int ni = 0; ni < 4; ++ni)
        acc[mi][ni] = __builtin_amdgcn_mfma_f32_16x16x32_bf16(af[mi], bfr[ni], acc[mi][ni], 0, 0, 0);
  }

#pragma unroll
  for (int ni = 0; ni < 4; ++ni) {
    int n = nBase + wx * 64 + ni * 16 + m16;
    float bb = BIAS ? bias[(long)batch * sBias_ + n] : 0.f;
#pragma unroll
    for (int mi = 0; mi < 4; ++mi) {
      int m0 = mBase + wy * 64 + mi * 16 + quad * 4;
      floatx4 v = acc[mi][ni];
#pragma unroll
      for (int rr = 0; rr < 4; ++rr)
        store_out(&C[(long)(m0 + rr) * N + n], v[rr] + bb);
    }
  }
}

// ---------------- reduce split-K partials of G to bf16 -----------------------
__global__ void g_reduce(const float* __restrict__ gp, ushort_t* __restrict__ gb) {
  int i = (blockIdx.x * 256 + threadIdx.x) * 4;  // 4 batches x 1M elements
  int b = i >> 20, off = i & 1048575;
  float4 p0 = *(const float4*)(gp + (long)b * 2097152 + off);
  float4 p1 = *(const float4*)(gp + (long)b * 2097152 + 1048576 + off);
  ushort4v o;
  o[0] = f2bf(p0.x + p1.x); o[1] = f2bf(p0.y + p1.y);
  o[2] = f2bf(p0.z + p1.z); o[3] = f2bf(p0.w + p1.w);
  *(ushort4v*)(gb + i) = o;
}

// ---------------- column sums: s[b][c] = sum_n Xbf[b][n][c] ------------------
__global__ void colsum(const ushort_t* __restrict__ X, float* __restrict__ s) {
  int b = blockIdx.x, ct = blockIdx.y;  // 4 x 16
  int t = threadIdx.x;
  int c8 = (t & 7) * 8, g = t >> 3;
  long base = (long)b * 4194304 + (long)ct * 64;
  float acc[8] = {};
  for (int n = g * 128; n < g * 128 + 128; ++n) {
    ushort8 v = *(const ushort8*)(X + base + (long)n * 1024 + c8);
#pragma unroll
    for (int i = 0; i < 8; ++i) acc[i] += bf2f(v[i]);
  }
  __shared__ float red[32 * 64];
#pragma unroll
  for (int i = 0; i < 8; ++i) red[g * 64 + c8 + i] = acc[i];
  __syncthreads();
  if (t < 64) {
    float sum = 0.f;
#pragma unroll
    for (int gg = 0; gg < 32; ++gg) sum += red[gg * 64 + t];
    s[b * 1024 + ct * 64 + t] = sum;
  }
}

// ---------------- u = Wk s, w = Wv s ----------------------------------------
__global__ void gemv_uw(const ushort_t* __restrict__ Wkbf, const ushort_t* __restrict__ Wvbf,
                        const float* __restrict__ s, float* __restrict__ u, float* __restrict__ w) {
  int b = blockIdx.x, rt = blockIdx.y;  // 4 x 8
  __shared__ float ss[1024];
  int t = threadIdx.x;
  *(float4*)(ss + t * 4) = *(const float4*)(s + b * 1024 + t * 4);
  __syncthreads();
  int wv = t >> 6, l = t & 63;
  int rl = l >> 3, j8 = (l & 7) * 8;
#pragma unroll
  for (int m = 0; m < 2; ++m) {
    const ushort_t* W = m ? Wvbf : Wkbf;
    float* o = m ? w : u;
    for (int rb = 0; rb < 128; rb += 32) {
      int row = rt * 128 + rb + wv * 8 + rl;
      float acc = 0.f;
      for (int k = 0; k < 1024; k += 64) {
        ushort8 wv8 = *(const ushort8*)(W + (long)row * 1024 + k + j8);
#pragma unroll
        for (int i = 0; i < 8; ++i) acc += bf2f(wv8[i]) * ss[k + j8 + i];
      }
      acc += __shfl_xor(acc, 1);
      acc += __shfl_xor(acc, 2);
      acc += __shfl_xor(acc, 4);
      if ((l & 7) == 0) o[b * 1024 + row] = acc;
    }
  }
}

// ---------------- ktv[b,h] = T1_b[h-rows]*Wv_h^T + rank-1 corrections -------
__global__ void ktv_small(const ushort_t* __restrict__ T1, const ushort_t* __restrict__ Wvbf,
                          const float* __restrict__ u, const float* __restrict__ w,
                          const float* __restrict__ bk, const float* __restrict__ bv,
                          float* __restrict__ ktv) {
  int bh = blockIdx.x;  // 64
  int b = bh >> 4, h = bh & 15;
  __shared__ ushort_t sA[64 * 32];
  __shared__ ushort_t sB[64 * 32];
  int t = threadIdx.x, wv = t >> 6, l = t & 63;
  int quad = l >> 4, m16 = l & 15;
  int r = l >> 2, pb = l & 3;
  int swzS = (r ^ (r >> 2)) & 3;
  int sCol = (pb ^ swzS) * 8;
  const ushort_t* gA = T1 + (long)b * 1048576 + (long)(h * 64 + wv * 16 + r) * 1024 + sCol;
  const ushort_t* gB = Wvbf + (long)(h * 64 + wv * 16 + r) * 1024 + sCol;
  ushort_t* lA = sA + wv * 512;
  ushort_t* lB = sB + wv * 512;
  int swzR = (m16 ^ (m16 >> 2)) & 3;
  int aOff = (wv * 16 + m16) * 32 + (quad ^ swzR) * 8;
  floatx4 acc[4] = {};
  for (int kt = 0; kt < 1024; kt += 32) {
    __syncthreads();
    gload_lds16(gA + kt, lA);
    gload_lds16(gB + kt, lB);
    __syncthreads();
    bf16x8 af = *(const bf16x8*)(sA + aOff);
#pragma unroll
    for (int j = 0; j < 4; ++j) {
      bf16x8 bf = *(const bf16x8*)(sB + (j * 16 + m16) * 32 + (quad ^ swzR) * 8);
      acc[j] = __builtin_amdgcn_mfma_f32_16x16x32_bf16(af, bf, acc[j], 0, 0, 0);
    }
  }
  float* p = ktv + (long)bh * 4096;
#pragma unroll
  for (int j = 0; j < 4; ++j) {
    int e = j * 16 + m16;
    float bve = bv[h * 64 + e];
    float wpe = w[b * 1024 + h * 64 + e] + 4096.f * bve;
#pragma unroll
    for (int rr = 0; rr < 4; ++rr) {
      int d = wv * 16 + quad * 4 + rr;
      float corr = u[b * 1024 + h * 64 + d] * bve + bk[h * 64 + d] * wpe;
      p[d * 64 + e] = acc[j][rr] + corr;
    }
  }
}

// ---------------- build W2T (bf16) and bias2 (fp32) -------------------------
__global__ void make_w2(const float* __restrict__ Wq, const float* __restrict__ bq,
                        const float* __restrict__ ktv, ushort_t* __restrict__ W2T,
                        float* __restrict__ bias2, float scale) {
  int bh = blockIdx.x, cq = blockIdx.y;
  int b = bh >> 4, h = bh & 15;
  __shared__ float sKTV[64 * 64];
  __shared__ float sW[64 * 64];
  int t = threadIdx.x;
  for (int i = t * 4; i < 4096; i += 1024)
    *(float4*)(sKTV + i) = *(const float4*)(ktv + (long)bh * 4096 + i);
  __syncthreads();
  if (cq == 0 && t < 64) {
    float s = 0.f;
    for (int d = 0; d < 64; ++d) s += bq[h * 64 + d] * sKTV[d * 64 + t];
    bias2[b * 1024 + h * 64 + t] = s * scale;
  }
  int e = t >> 2, c0 = (t & 3) * 16;
  for (int ct = cq * 256; ct < cq * 256 + 256; ct += 64) {
    __syncthreads();
    {
      int d = t >> 2, cc = (t & 3) * 16;
#pragma unroll
      for (int j = 0; j < 16; j += 4)
        *(float4*)(sW + d * 64 + cc + j) =
            *(const float4*)(Wq + (long)(h * 64 + d) * 1024 + ct + cc + j);
    }
    __syncthreads();
    float outv[16] = {};
    for (int d = 0; d < 64; ++d) {
      float kv = sKTV[d * 64 + e];
#pragma unroll
      for (int j = 0; j < 16; ++j) outv[j] += sW[d * 64 + c0 + j] * kv;
    }
    ushort8 o0, o1;
#pragma unroll
    for (int j = 0; j < 8; ++j) { o0[j] = f2bf(outv[j] * scale); o1[j] = f2bf(outv[8 + j] * scale); }
    ushort_t* dst = W2T + ((long)(b * 1024 + h * 64 + e)) * 1024 + ct + c0;
    *(ushort8*)dst = o0;
    *(ushort8*)(dst + 8) = o1;
  }
}

// ---------------- launch -----------------------------------------------------
extern "C" void kernel_launch(void* const* d_in, const int* in_sizes, int n_in,
                              void* d_out, int out_size, void* d_ws, size_t ws_size,
                              hipStream_t stream) {
  (void)in_sizes; (void)n_in; (void)out_size; (void)ws_size;
  const float* tens = (const float*)d_in[0];
  const float* Wq = (const float*)d_in[1];
  const float* bq = (const float*)d_in[2];
  const float* Wk = (const float*)d_in[3];
  const float* bk = (const float*)d_in[4];
  const float* Wv = (const float*)d_in[5];
  const float* bv = (const float*)d_in[6];
  float* out = (float*)d_out;

  char* wsp = (char*)d_ws;
  ushort_t* Xbf  = (ushort_t*)(wsp);               // 33,554,432 B (live to end)
  ushort_t* XTbf = (ushort_t*)(wsp + 33554432);    // 33,554,432 B (dead after G)
  float*    Gpart= (float*)(wsp + 67108864);       // 33,554,432 B (dead after reduce)
  ushort_t* T1   = (ushort_t*)(wsp + 67108864);    //  8,388,608 B (aliases dead Gpart)
  ushort_t* W2T  = (ushort_t*)(wsp + 75497472);    //  8,388,608 B (aliases dead Gpart)
  float*    ktv  = (float*)(wsp + 83886080);       //  1,048,576 B (aliases dead Gpart)
  ushort_t* Gbf  = (ushort_t*)(wsp + 100663296);   //  8,388,608 B
  ushort_t* Wkbf = (ushort_t*)(wsp + 109051904);   //  2,097,152 B
  ushort_t* Wvbf = (ushort_t*)(wsp + 111149056);   //  2,097,152 B
  float*    s    = (float*)(wsp + 113246208);      //     16,384 B
  float*    u    = (float*)(wsp + 113262592);      //     16,384 B
  float*    w    = (float*)(wsp + 113278976);      //     16,384 B
  float*    bias2= (float*)(wsp + 113295360);      //     16,384 B

  const float scale = (1.0f / 8.0f) / 64.0f;  // 1/sqrt(DH)/sqrt(N)

  hipLaunchKernelGGL(cvt_tr, dim3(64, 16, 4), dim3(256), 0, stream, tens, Xbf, XTbf);
  hipLaunchKernelGGL(cvt_f32_bf16, dim3(512), dim3(256), 0, stream, Wk, Wkbf, 1048576);
  hipLaunchKernelGGL(cvt_f32_bf16, dim3(512), dim3(256), 0, stream, Wv, Wvbf, 1048576);
  hipLaunchKernelGGL(colsum, dim3(4, 16), dim3(256), 0, stream, Xbf, s);

  // G_b = X_b^T X_b via XT (NT gemm, K=4096 split into 2 slices of 2048) -> fp32 partials
  hipLaunchKernelGGL((gemm_bt<float, false, 2048, 4096, 2>), dim3(8, 8, 8), dim3(256), 0, stream,
                     XTbf, XTbf, (const float*)nullptr, Gpart, 1024, 1024,
                     4194304L, 4194304L, 0L, 1048576L);
  hipLaunchKernelGGL(g_reduce, dim3(4096), dim3(256), 0, stream, Gpart, Gbf);

  hipLaunchKernelGGL(gemv_uw, dim3(4, 8), dim3(256), 0, stream, Wkbf, Wvbf, s, u, w);

  // T1_b = Wk G_b (G symmetric -> NT gemm) -> bf16
  hipLaunchKernelGGL((gemm_bt<ushort_t, false, 1024, 1024, 1>), dim3(8, 8, 4), dim3(256), 0, stream,
                     Wkbf, Gbf, (const float*)nullptr, T1, 1024, 1024,
                     0L, 1048576L, 0L, 1048576L);

  hipLaunchKernelGGL(ktv_small, dim3(64), dim3(256), 0, stream, T1, Wvbf, u, w, bk, bv, ktv);
  hipLaunchKernelGGL(make_w2, dim3(64, 4), dim3(256), 0, stream, Wq, bq, ktv, W2T, bias2, scale);

  hipLaunchKernelGGL((gemm_bt<float, true, 1024, 1024, 1>), dim3(8, 32, 4), dim3(256), 0, stream,
                     Xbf, W2T, bias2, out, 4096, 1024,
                     4194304L, 1048576L, 1024L, 4194304L);
}